// Round 15
// baseline (732.216 us; speedup 1.0000x reference)
//
#include <hip/hip_runtime.h>
#include <hip/hip_bf16.h>
#include <math.h>

#define B_ 8
#define T_ 1024
#define D_ 256
#define NH_ 4
#define N_ 256
#define EPS_ 1e-5f

typedef __attribute__((ext_vector_type(8))) short short8_t;
typedef __attribute__((ext_vector_type(4))) float floatx4;

__device__ inline unsigned short f2bf(float f) {
    unsigned u = __builtin_bit_cast(unsigned, f);
    u += 0x7FFFu + ((u >> 16) & 1u);          // round-to-nearest-even
    return (unsigned short)(u >> 16);
}
__device__ inline float bf2f(unsigned short h) {
    return __builtin_bit_cast(float, (unsigned)h << 16);
}

// async global->LDS, 16 B per lane; lds base wave-uniform, HW adds lane*16
__device__ inline void gload_lds16(const unsigned short* g, unsigned short* l) {
    __builtin_amdgcn_global_load_lds(
        (const __attribute__((address_space(1))) unsigned int*)g,
        (__attribute__((address_space(3))) unsigned int*)l, 16, 0, 0);
}

// ---------- helpers ----------
__device__ inline float2 block_stats_256(float v, float* red) {
    float s1 = v, s2 = v * v;
    #pragma unroll
    for (int o = 32; o > 0; o >>= 1) { s1 += __shfl_down(s1, o); s2 += __shfl_down(s2, o); }
    int wave = threadIdx.x >> 6, lane = threadIdx.x & 63;
    __syncthreads();
    if (lane == 0) { red[wave] = s1; red[4 + wave] = s2; }
    __syncthreads();
    float S1 = red[0] + red[1] + red[2] + red[3];
    float S2 = red[4] + red[5] + red[6] + red[7];
    float mean = S1 * (1.f / 256.f);
    float var  = S2 * (1.f / 256.f) - mean * mean;
    return make_float2(mean, var);
}

// ---------- weight transpose + split ----------
__global__ __launch_bounds__(256) void k_wT(
    const float* __restrict__ in, unsigned short* __restrict__ outh,
    unsigned short* __restrict__ outl, int R, int C)
{
    __shared__ float tile[64][65];
    int c0 = blockIdx.x * 64, r0 = blockIdx.y * 64, h = blockIdx.z;
    in += (size_t)h * R * C;
    for (int i = threadIdx.x; i < 4096; i += 256) {
        int r = i >> 6, c = i & 63;
        tile[r][c] = in[(size_t)(r0 + r) * C + c0 + c];
    }
    __syncthreads();
    for (int i = threadIdx.x; i < 4096; i += 256) {
        int c = i >> 6, r = i & 63;
        float v = tile[r][c];
        unsigned short hb = f2bf(v);
        size_t o = (size_t)(h * C + c0 + c) * R + r0 + r;
        outh[o] = hb;
        outl[o] = f2bf(v - bf2f(hb));
    }
}

// ---------- input projection + LN (+ bf16 hi/lo split of x) ----------
__global__ __launch_bounds__(256) void k_input_ln(
    const float* __restrict__ inputs, const float* __restrict__ in_w,
    const float* __restrict__ in_b, float* __restrict__ x,
    unsigned short* __restrict__ xh, unsigned short* __restrict__ xl)
{
    __shared__ float red[8];
    int row = blockIdx.x;
    int d = threadIdx.x;
    float v = inputs[row] * in_w[d] + in_b[d];
    float2 mv = block_stats_256(v, red);
    float o = (v - mv.x) * rsqrtf(mv.y + EPS_);
    size_t idx = (size_t)row * D_ + d;
    x[idx] = o;
    unsigned short hb = f2bf(o);
    xh[idx] = hb;
    xl[idx] = f2bf(o - bf2f(hb));
}

// ---------- split-bf16 MFMA GEMM ----------
// BK=64: 4 K-steps instead of 8 — halves the exposed staging drains/barriers
// while doubling per-step MFMA (96). Sync staging + (256,2) kept: the second
// co-resident block provides overlap (round-12 lesson: async dbuf fails here).
// MODE 2 split-K-4: blockIdx.z = kz, partials summed in k_resid_ln.
#define PG 72   // LDS pitch (64 + 8)
template<int MODE>
__global__ __launch_bounds__(256, 2) void k_gemm_mfma(
    const unsigned short* __restrict__ Ah, const unsigned short* __restrict__ Al,
    const unsigned short* __restrict__ Wh, const unsigned short* __restrict__ Wl,
    const unsigned short* __restrict__ xsh, const unsigned short* __restrict__ xsl,
    unsigned short* __restrict__ outh, unsigned short* __restrict__ outl,
    float* __restrict__ outf)
{
    constexpr int K = (MODE == 2) ? 1024 : 256;
    __shared__ unsigned short As_h[128 * PG], As_l[128 * PG];   // 18.4 KB each
    __shared__ unsigned short Ws_h[128 * PG], Ws_l[128 * PG];   // total 73.7 KB
    int tid = threadIdx.x;
    int w = tid >> 6, lane = tid & 63, quad = lane >> 4, l16 = lane & 15;
    int wm = w >> 1, wn = w & 1;
    int m0 = blockIdx.y * 128, n0x = blockIdx.x * 128;
    size_t a_row0, w_row0, out_row0;
    int col0;
    int koff = 0, kend = K;
    if (MODE == 1) {
        int bh = blockIdx.z;
        a_row0 = (size_t)bh * 1024 + m0;
        w_row0 = (size_t)((bh & 3) * 256 + n0x);
        out_row0 = (size_t)(bh >> 2) * 1024 + m0;
        col0 = (bh & 3) * 256 + n0x;
    } else {
        a_row0 = m0; w_row0 = n0x; out_row0 = m0; col0 = n0x;
        if (MODE == 2) { koff = blockIdx.z * 256; kend = koff + 256; }
    }
    floatx4 acc[4][4];
    #pragma unroll
    for (int mt = 0; mt < 4; mt++)
        #pragma unroll
        for (int nt = 0; nt < 4; nt++)
            acc[mt][nt] = (floatx4){0.f, 0.f, 0.f, 0.f};

    for (int k0 = koff; k0 < kend; k0 += 64) {
        #pragma unroll
        for (int it = 0; it < 4; it++) {
            int fl = tid + it * 256;
            int row = fl >> 3, ch = fl & 7;     // 128 rows x 8 chunks of 8
            size_t ga = (a_row0 + row) * (size_t)K + k0 + ch * 8;
            size_t gw = (w_row0 + row) * (size_t)K + k0 + ch * 8;
            *(short8_t*)&As_h[row * PG + ch * 8] = *(const short8_t*)(Ah + ga);
            *(short8_t*)&As_l[row * PG + ch * 8] = *(const short8_t*)(Al + ga);
            *(short8_t*)&Ws_h[row * PG + ch * 8] = *(const short8_t*)(Wh + gw);
            *(short8_t*)&Ws_l[row * PG + ch * 8] = *(const short8_t*)(Wl + gw);
        }
        __syncthreads();
        #pragma unroll
        for (int kc2 = 0; kc2 < 2; kc2++) {
            int ko = kc2 * 32 + quad * 8;
            short8_t afh[4], afl[4], bfh[4], bfl[4];
            #pragma unroll
            for (int mt = 0; mt < 4; mt++) {
                afh[mt] = *(const short8_t*)&As_h[(wm * 64 + mt * 16 + l16) * PG + ko];
                afl[mt] = *(const short8_t*)&As_l[(wm * 64 + mt * 16 + l16) * PG + ko];
            }
            #pragma unroll
            for (int nt = 0; nt < 4; nt++) {
                bfh[nt] = *(const short8_t*)&Ws_h[(wn * 64 + nt * 16 + l16) * PG + ko];
                bfl[nt] = *(const short8_t*)&Ws_l[(wn * 64 + nt * 16 + l16) * PG + ko];
            }
            #pragma unroll
            for (int mt = 0; mt < 4; mt++)
                #pragma unroll
                for (int nt = 0; nt < 4; nt++) {
                    acc[mt][nt] = __builtin_amdgcn_mfma_f32_16x16x32_bf16(afh[mt], bfh[nt], acc[mt][nt], 0, 0, 0);
                    acc[mt][nt] = __builtin_amdgcn_mfma_f32_16x16x32_bf16(afh[mt], bfl[nt], acc[mt][nt], 0, 0, 0);
                    acc[mt][nt] = __builtin_amdgcn_mfma_f32_16x16x32_bf16(afl[mt], bfh[nt], acc[mt][nt], 0, 0, 0);
                }
        }
        __syncthreads();
    }

    #pragma unroll
    for (int mt = 0; mt < 4; mt++) {
        #pragma unroll
        for (int r = 0; r < 4; r++) {
            size_t grow = out_row0 + wm * 64 + mt * 16 + quad * 4 + r;
            #pragma unroll
            for (int nt = 0; nt < 4; nt++) {
                int gcol = col0 + wn * 64 + nt * 16 + l16;
                float v = acc[mt][nt][r];
                if (MODE == 0) {
                    v = fmaxf(v, 0.f);
                    size_t o = grow * 1024 + gcol;
                    unsigned short hb = f2bf(v);
                    outh[o] = hb;
                    outl[o] = f2bf(v - bf2f(hb));
                } else if (MODE == 1) {
                    float y = fmaxf(v, 0.f);
                    size_t o = grow * 1024 + gcol;
                    float xv = bf2f(xsh[o]) + bf2f(xsl[o]);
                    float p = xv * y;
                    unsigned short hb = f2bf(p);
                    outh[o] = hb;
                    outl[o] = f2bf(p - bf2f(hb));
                } else {
                    outf[(size_t)blockIdx.z * 2097152 + grow * 256 + gcol] = v;
                }
            }
        }
    }
}

// ---------- rope: xs hi/lo (B,T,NH,N) -> qr hi/lo (B,NH,T,N) bf16 ----------
// fast-math device intrinsics: __expf / __sinf / __cosf (err ~1e-6 << budget)
__global__ __launch_bounds__(256) void k_rope_bf16(
    const unsigned short* __restrict__ xsh, const unsigned short* __restrict__ xsl,
    unsigned short* __restrict__ qh, unsigned short* __restrict__ ql)
{
    int tid = blockIdx.x * 256 + threadIdx.x;
    int e0 = tid * 8;
    int n0 = e0 & 255;
    int t  = (e0 >> 8) & 1023;
    int bh = e0 >> 18;
    int h = bh & 3, b = bh >> 2;
    size_t src = (((size_t)(b * T_ + t) * NH_ + h) << 8) + n0;
    short8_t vh = *(const short8_t*)(xsh + src);
    short8_t vl = *(const short8_t*)(xsl + src);
    float v[8];
    #pragma unroll
    for (int i = 0; i < 8; i++)
        v[i] = bf2f((unsigned short)vh[i]) + bf2f((unsigned short)vl[i]);
    float cc[4], ss[4];
    int p0 = n0 >> 1;
    #pragma unroll
    for (int i = 0; i < 4; i++) {
        int p = p0 + i;
        int j = p & 63;
        int pos = (p < 64) ? (t & 31) : (t >> 5);
        float f = __expf((float)j * -0.14391156f);   // 10000^(-j/64) = e^(-j*ln(1e4)/64)
        float ang = (float)pos * f;
        ss[i] = __sinf(ang);
        cc[i] = __cosf(ang);
    }
    float r[8];
    r[0] = v[0] * cc[0] - v[1] * ss[0];
    r[1] = v[0] * ss[0] + v[1] * cc[0];
    r[2] = v[2] * cc[1] - v[3] * ss[1];
    r[3] = v[2] * ss[1] + v[3] * cc[1];
    r[4] = v[4] * cc[2] - v[5] * ss[2];
    r[5] = v[4] * ss[2] + v[5] * cc[2];
    r[6] = v[6] * cc[3] - v[7] * ss[3];
    r[7] = v[6] * ss[3] + v[7] * cc[3];
    short8_t oh, ol;
    #pragma unroll
    for (int i = 0; i < 8; i++) {
        unsigned short hbits = f2bf(r[i]);
        oh[i] = (short)hbits;
        ol[i] = (short)f2bf(r[i] - bf2f(hbits));
    }
    *(short8_t*)(qh + e0) = oh;
    *(short8_t*)(ql + e0) = ol;
}

// ---------- x (B,T,D) fp32 -> Vf hi/lo fragment-order bf16 ----------
__global__ __launch_bounds__(256) void k_xT(const float* __restrict__ x,
                                            unsigned short* __restrict__ Vfh,
                                            unsigned short* __restrict__ Vfl)
{
    __shared__ float tile[64][65];   // [t_local][d_local]
    int t0 = blockIdx.x * 64, d0 = blockIdx.y * 64, b = blockIdx.z;
    const float* src = x + ((size_t)b * T_ + t0) * D_ + d0;
    for (int i = threadIdx.x; i < 1024; i += 256) {
        int r = i >> 4, c = i & 15;
        float4 v = *(const float4*)(src + (size_t)r * D_ + c * 4);
        tile[r][c * 4 + 0] = v.x;
        tile[r][c * 4 + 1] = v.y;
        tile[r][c * 4 + 2] = v.z;
        tile[r][c * 4 + 3] = v.w;
    }
    __syncthreads();
    for (int i = threadIdx.x; i < 1024; i += 256) {
        int d = i >> 4, c = i & 15;          // d_local, t-group (4 consecutive t)
        int tg = t0 + c * 4;
        int jj = tg >> 5, qd = (tg >> 3) & 3, i8 = tg & 7;   // i8 in {0,4}
        int dg = d0 + d;
        int tn = dg >> 4, s16 = dg & 15;
        size_t o = (((size_t)b * 32 + jj) * 16 + tn) * 512 + (qd * 16 + s16) * 8 + i8;
        float v0 = tile[c * 4 + 0][d], v1 = tile[c * 4 + 1][d];
        float v2 = tile[c * 4 + 2][d], v3 = tile[c * 4 + 3][d];
        ushort4 oh, ol;
        oh.x = f2bf(v0); ol.x = f2bf(v0 - bf2f(oh.x));
        oh.y = f2bf(v1); ol.y = f2bf(v1 - bf2f(oh.y));
        oh.z = f2bf(v2); ol.z = f2bf(v2 - bf2f(oh.z));
        oh.w = f2bf(v3); ol.w = f2bf(v3 - bf2f(oh.w));
        *(ushort4*)(Vfh + o) = oh;
        *(ushort4*)(Vfl + o) = ol;
    }
}

// ---------- fused split-bf16 MFMA flash attention + /l + LayerNorm ----------
// (unchanged: V-LDS dbuf + fixed-shift softmax + QK ILP)
#define PPW 36   // per-wave P pitch (32 + 4)

__global__ __launch_bounds__(512, 1) void k_attn_mfma(
    const unsigned short* __restrict__ qr_h, const unsigned short* __restrict__ qr_l,
    const unsigned short* __restrict__ Vf_h, const unsigned short* __restrict__ Vf_l,
    unsigned short* __restrict__ ykvh, unsigned short* __restrict__ ykvl)
{
    __shared__ unsigned short K_h[2][16 * 512];   // 32 KB (2 buf, frag order)
    __shared__ unsigned short K_l[2][16 * 512];   // 32 KB
    __shared__ unsigned short V_h[2][16 * 512];   // 32 KB
    __shared__ unsigned short V_l[2][16 * 512];   // 32 KB
    __shared__ unsigned short P_h[8][16 * PPW];   // 9216 B (per-wave private)
    __shared__ unsigned short P_l[8][16 * PPW];   // 9216 B

    int tid = threadIdx.x;
    int w = tid >> 6, lane = tid & 63, quad = lane >> 4, l16 = lane & 15;
    int gid = blockIdx.x;
    int bh = gid & 31, tile = gid >> 5, b = bh >> 2;   // XCD swizzle
    int t0q = tile * 128;
    const unsigned short* qhb = qr_h + (size_t)bh * T_ * N_;
    const unsigned short* qlb = qr_l + (size_t)bh * T_ * N_;
    const unsigned short* vhb = Vf_h + (size_t)b * 32 * 16 * 512;
    const unsigned short* vlb = Vf_l + (size_t)b * 32 * 16 * 512;

    // Q A-frags: wave's 16 rows, full feature dim (8 kc chunks), hi+lo
    short8_t qfh[8], qfl[8];
    #pragma unroll
    for (int kc = 0; kc < 8; kc++) {
        size_t o = (size_t)(t0q + w * 16 + l16) * N_ + kc * 32 + quad * 8;
        qfh[kc] = *(const short8_t*)(qhb + o);
        qfl[kc] = *(const short8_t*)(qlb + o);
    }

    floatx4 O[16];
    #pragma unroll
    for (int tn = 0; tn < 16; tn++) O[tn] = (floatx4){0.f, 0.f, 0.f, 0.f};
    float lst[4] = {0.f, 0.f, 0.f, 0.f};   // per-LANE partial row sums
    const float scale = 0.0625f;   // 1/sqrt(256)

    // preamble: stage K and V tile 0 into buffer 0 (wave w: slots 2w, 2w+1)
    #pragma unroll
    for (int s = 0; s < 2; s++) {
        int slot = w * 2 + s;
        int ct = slot >> 3, kc = slot & 7;
        size_t go = (size_t)(ct * 16 + l16) * N_ + kc * 32 + quad * 8;
        gload_lds16(qhb + go, &K_h[0][slot * 512]);
        gload_lds16(qlb + go, &K_l[0][slot * 512]);
        size_t vo = ((size_t)slot << 9) + lane * 8;
        gload_lds16(vhb + vo, &V_h[0][slot * 512]);
        gload_lds16(vlb + vo, &V_l[0][slot * 512]);
    }

    for (int j = 0; j < 32; j++) {
        int buf = j & 1;
        __syncthreads();            // tiles j ready; buf^1 free
        if (j < 31) {               // async-stage K & V tile j+1 (full step to land)
            #pragma unroll
            for (int s = 0; s < 2; s++) {
                int slot = w * 2 + s;
                int ct = slot >> 3, kc = slot & 7;
                size_t go = (size_t)((j + 1) * 32 + ct * 16 + l16) * N_ + kc * 32 + quad * 8;
                gload_lds16(qhb + go, &K_h[buf ^ 1][slot * 512]);
                gload_lds16(qlb + go, &K_l[buf ^ 1][slot * 512]);
                size_t vo = ((size_t)((j + 1) * 16 + slot) << 9) + lane * 8;
                gload_lds16(vhb + vo, &V_h[buf ^ 1][slot * 512]);
                gload_lds16(vlb + vo, &V_l[buf ^ 1][slot * 512]);
            }
        }

        // QK^T: 3 independent accumulator chains per ct (ILP)
        floatx4 sc[2];
        #pragma unroll
        for (int ct = 0; ct < 2; ct++) {
            floatx4 a_hh = (floatx4){0.f, 0.f, 0.f, 0.f};
            floatx4 a_hl = (floatx4){0.f, 0.f, 0.f, 0.f};
            floatx4 a_lh = (floatx4){0.f, 0.f, 0.f, 0.f};
            #pragma unroll
            for (int kc = 0; kc < 8; kc++) {
                short8_t bkh = *(const short8_t*)&K_h[buf][(ct * 8 + kc) * 512 + lane * 8];
                short8_t bkl = *(const short8_t*)&K_l[buf][(ct * 8 + kc) * 512 + lane * 8];
                a_hh = __builtin_amdgcn_mfma_f32_16x16x32_bf16(qfh[kc], bkh, a_hh, 0, 0, 0);
                a_hl = __builtin_amdgcn_mfma_f32_16x16x32_bf16(qfh[kc], bkl, a_hl, 0, 0, 0);
                a_lh = __builtin_amdgcn_mfma_f32_16x16x32_bf16(qfl[kc], bkh, a_lh, 0, 0, 0);
            }
            sc[ct] = (a_hh + a_hl) + a_lh;
        }

        // fixed-shift softmax (row = w*16 + quad*4 + r); no cross-lane ops
        #pragma unroll
        for (int r = 0; r < 4; r++) {
            float p0 = __expf(sc[0][r] * scale - 8.f);
            float p1 = __expf(sc[1][r] * scale - 8.f);
            lst[r] += p0 + p1;
            unsigned short p0h = f2bf(p0), p1h = f2bf(p1);
            P_h[w][(quad * 4 + r) * PPW + l16]      = p0h;
            P_h[w][(quad * 4 + r) * PPW + 16 + l16] = p1h;
            P_l[w][(quad * 4 + r) * PPW + l16]      = f2bf(p0 - bf2f(p0h));
            P_l[w][(quad * 4 + r) * PPW + 16 + l16] = f2bf(p1 - bf2f(p1h));
        }

        // P C-layout -> A-layout via same-wave LDS round-trip (no barrier)
        short8_t pah = *(const short8_t*)&P_h[w][l16 * PPW + quad * 8];
        short8_t pal = *(const short8_t*)&P_l[w][l16 * PPW + quad * 8];

        // PV (split 3-term): V frags from LDS, conflict-free ds_read_b128
        #pragma unroll
        for (int tn = 0; tn < 16; tn++) {
            short8_t vbh = *(const short8_t*)&V_h[buf][tn * 512 + lane * 8];
            short8_t vbl = *(const short8_t*)&V_l[buf][tn * 512 + lane * 8];
            O[tn] = __builtin_amdgcn_mfma_f32_16x16x32_bf16(pah, vbh, O[tn], 0, 0, 0);
            O[tn] = __builtin_amdgcn_mfma_f32_16x16x32_bf16(pah, vbl, O[tn], 0, 0, 0);
            O[tn] = __builtin_amdgcn_mfma_f32_16x16x32_bf16(pal, vbh, O[tn], 0, 0, 0);
        }
    }

    // epilogue: reduce l across the quad's 16 lanes, then yKV = LN_d(O / l)
    size_t obase = ((size_t)bh * T_ + t0q + w * 16) * D_;
    #pragma unroll
    for (int r = 0; r < 4; r++) {
        float lsum = lst[r];
        #pragma unroll
        for (int o = 1; o < 16; o <<= 1) lsum += __shfl_xor(lsum, o);
        float li = 1.f / lsum;
        float s1 = 0.f, s2 = 0.f;
        #pragma unroll
        for (int tn = 0; tn < 16; tn++) { float v = O[tn][r]; s1 += v; s2 += v * v; }
        #pragma unroll
        for (int o = 1; o < 16; o <<= 1) { s1 += __shfl_xor(s1, o); s2 += __shfl_xor(s2, o); }
        float mean = s1 * li * (1.f / 256.f);
        float e2   = s2 * li * li * (1.f / 256.f);
        float var  = e2 - mean * mean;
        float rs = rsqrtf(var + EPS_);
        float a = li * rs, bb = mean * rs;
        int row = quad * 4 + r;
        #pragma unroll
        for (int tn = 0; tn < 16; tn++) {
            float v = O[tn][r] * a - bb;
            size_t o = obase + (size_t)row * D_ + tn * 16 + l16;
            unsigned short hb = f2bf(v);
            ykvh[o] = hb;
            ykvl[o] = f2bf(v - bf2f(hb));
        }
    }
}

// ---------- residual + double LN: sums 4 split-K partials of ymlp ----------
__global__ __launch_bounds__(256) void k_resid_ln(float* __restrict__ x,
                                                  const float* __restrict__ ymlp,
                                                  unsigned short* __restrict__ xh,
                                                  unsigned short* __restrict__ xl)
{
    __shared__ float red[8];
    int row = blockIdx.x, d = threadIdx.x;
    size_t o = (size_t)row * D_ + d;
    float y = ymlp[o] + ymlp[o + 2097152] + ymlp[o + 2 * 2097152] + ymlp[o + 3 * 2097152];
    float2 mv1 = block_stats_256(y, red);
    float v = x[o] + (y - mv1.x) * rsqrtf(mv1.y + EPS_);
    float2 mv2 = block_stats_256(v, red);
    float out = (v - mv2.x) * rsqrtf(mv2.y + EPS_);
    x[o] = out;
    unsigned short hb = f2bf(out);
    xh[o] = hb;
    xl[o] = f2bf(out - bf2f(hb));
}

// ---------- logits ----------
__global__ __launch_bounds__(256) void k_logits(
    const float* __restrict__ x, const float* __restrict__ out_w,
    const float* __restrict__ out_b, float* __restrict__ out)
{
    __shared__ float red[4];
    int row = blockIdx.x, d = threadIdx.x;
    float v = x[(size_t)row * D_ + d] * out_w[d];
    #pragma unroll
    for (int o = 32; o > 0; o >>= 1) v += __shfl_down(v, o);
    int wave = d >> 6, lane = d & 63;
    if (lane == 0) red[wave] = v;
    __syncthreads();
    if (d == 0) out[row] = red[0] + red[1] + red[2] + red[3] + out_b[0];
}

extern "C" void kernel_launch(void* const* d_in, const int* in_sizes, int n_in,
                              void* d_out, int out_size, void* d_ws, size_t ws_size,
                              hipStream_t stream)
{
    (void)in_sizes; (void)n_in; (void)out_size;
    if (ws_size < ((size_t)115 << 20)) return;

    const float* inputs    = (const float*)d_in[0];
    const float* in_w      = (const float*)d_in[1];
    const float* in_b      = (const float*)d_in[2];
    const float* encoder   = (const float*)d_in[3];
    const float* encoder_v = (const float*)d_in[4];
    const float* decoder   = (const float*)d_in[5];
    const float* out_w     = (const float*)d_in[6];
    const float* out_b     = (const float*)d_in[7];

    char* wsb = (char*)d_ws;
    float* x             = (float*)(wsb);                                 //  8 MB fp32 (B,T,D)
    unsigned short* x_h  = (unsigned short*)(wsb + ((size_t)8  << 20));   //  4 MB bf16 hi
    unsigned short* x_l  = (unsigned short*)(wsb + ((size_t)12 << 20));   //  4 MB lo
    unsigned short* Vf_h = x_h;                                           //  ALIAS (disjoint phases)
    unsigned short* Vf_l = x_l;
    unsigned short* xs_h = (unsigned short*)(wsb + ((size_t)16 << 20));   // 16 MB (B,T,NH*N) hi
    unsigned short* xs_l = (unsigned short*)(wsb + ((size_t)32 << 20));   // 16 MB lo
    float* ymlp          = (float*)(wsb + ((size_t)16 << 20));            // 32 MB fp32 x4 partials,
                                                                          //  ALIASES xs (dead there)
    unsigned short* qr_h = (unsigned short*)(wsb + ((size_t)48 << 20));   // 16 MB (B,NH,T,N) hi
    unsigned short* qr_l = (unsigned short*)(wsb + ((size_t)64 << 20));   // 16 MB lo
    unsigned short* xy_h = qr_h;                                          //  ALIAS: xy after attn
    unsigned short* xy_l = qr_l;
    unsigned short* ykv_h = (unsigned short*)(wsb + ((size_t)80 << 20));  // 16 MB (B,NH,T,D) hi
    unsigned short* ykv_l = (unsigned short*)(wsb + ((size_t)96 << 20));  // 16 MB lo
    char* wbase = wsb + ((size_t)112 << 20);                              //  3 MB weights
    unsigned short* encT_h = (unsigned short*)(wbase);
    unsigned short* encT_l = (unsigned short*)(wbase + 0x80000);
    unsigned short* evT_h  = (unsigned short*)(wbase + 2 * 0x80000);
    unsigned short* evT_l  = (unsigned short*)(wbase + 3 * 0x80000);
    unsigned short* decT_h = (unsigned short*)(wbase + 4 * 0x80000);
    unsigned short* decT_l = (unsigned short*)(wbase + 5 * 0x80000);

    k_wT<<<dim3(4, 4, 4), 256, 0, stream>>>(encoder,   encT_h, encT_l, 256, 256);
    k_wT<<<dim3(4, 4, 4), 256, 0, stream>>>(encoder_v, evT_h,  evT_l,  256, 256);
    k_wT<<<dim3(4, 16, 1), 256, 0, stream>>>(decoder,  decT_h, decT_l, 1024, 256);

    k_input_ln<<<B_ * T_, 256, 0, stream>>>(inputs, in_w, in_b, x, x_h, x_l);
    for (int l = 0; l < 3; l++) {
        k_gemm_mfma<0><<<dim3(8, 64, 1), 256, 0, stream>>>(
            x_h, x_l, encT_h, encT_l, nullptr, nullptr, xs_h, xs_l, nullptr);
        k_rope_bf16<<<4096, 256, 0, stream>>>(xs_h, xs_l, qr_h, qr_l);
        k_xT<<<dim3(16, 4, 8), 256, 0, stream>>>(x, Vf_h, Vf_l);
        k_attn_mfma<<<256, 512, 0, stream>>>(qr_h, qr_l, Vf_h, Vf_l, ykv_h, ykv_l);
        k_gemm_mfma<1><<<dim3(2, 8, 32), 256, 0, stream>>>(
            ykv_h, ykv_l, evT_h, evT_l, xs_h, xs_l, xy_h, xy_l, nullptr);
        k_gemm_mfma<2><<<dim3(2, 64, 4), 256, 0, stream>>>(
            xy_h, xy_l, decT_h, decT_l, nullptr, nullptr, nullptr, nullptr, ymlp);
        k_resid_ln<<<B_ * T_, 256, 0, stream>>>(x, ymlp, x_h, x_l);
    }
    k_logits<<<B_ * T_, 256, 0, stream>>>(x, out_w, out_b, (float*)d_out);
}

// Round 16
// 724.946 us; speedup vs baseline: 1.0100x; 1.0100x over previous
//
#include <hip/hip_runtime.h>
#include <hip/hip_bf16.h>
#include <math.h>

#define B_ 8
#define T_ 1024
#define D_ 256
#define NH_ 4
#define N_ 256
#define EPS_ 1e-5f

typedef __attribute__((ext_vector_type(8))) short short8_t;
typedef __attribute__((ext_vector_type(4))) float floatx4;

__device__ inline unsigned short f2bf(float f) {
    unsigned u = __builtin_bit_cast(unsigned, f);
    u += 0x7FFFu + ((u >> 16) & 1u);          // round-to-nearest-even
    return (unsigned short)(u >> 16);
}
__device__ inline float bf2f(unsigned short h) {
    return __builtin_bit_cast(float, (unsigned)h << 16);
}

// async global->LDS, 16 B per lane; lds base wave-uniform, HW adds lane*16
__device__ inline void gload_lds16(const unsigned short* g, unsigned short* l) {
    __builtin_amdgcn_global_load_lds(
        (const __attribute__((address_space(1))) unsigned int*)g,
        (__attribute__((address_space(3))) unsigned int*)l, 16, 0, 0);
}

// ---------- helpers ----------
__device__ inline float2 block_stats_256(float v, float* red) {
    float s1 = v, s2 = v * v;
    #pragma unroll
    for (int o = 32; o > 0; o >>= 1) { s1 += __shfl_down(s1, o); s2 += __shfl_down(s2, o); }
    int wave = threadIdx.x >> 6, lane = threadIdx.x & 63;
    __syncthreads();
    if (lane == 0) { red[wave] = s1; red[4 + wave] = s2; }
    __syncthreads();
    float S1 = red[0] + red[1] + red[2] + red[3];
    float S2 = red[4] + red[5] + red[6] + red[7];
    float mean = S1 * (1.f / 256.f);
    float var  = S2 * (1.f / 256.f) - mean * mean;
    return make_float2(mean, var);
}

// ---------- weight transpose + split ----------
__global__ __launch_bounds__(256) void k_wT(
    const float* __restrict__ in, unsigned short* __restrict__ outh,
    unsigned short* __restrict__ outl, int R, int C)
{
    __shared__ float tile[64][65];
    int c0 = blockIdx.x * 64, r0 = blockIdx.y * 64, h = blockIdx.z;
    in += (size_t)h * R * C;
    for (int i = threadIdx.x; i < 4096; i += 256) {
        int r = i >> 6, c = i & 63;
        tile[r][c] = in[(size_t)(r0 + r) * C + c0 + c];
    }
    __syncthreads();
    for (int i = threadIdx.x; i < 4096; i += 256) {
        int c = i >> 6, r = i & 63;
        float v = tile[r][c];
        unsigned short hb = f2bf(v);
        size_t o = (size_t)(h * C + c0 + c) * R + r0 + r;
        outh[o] = hb;
        outl[o] = f2bf(v - bf2f(hb));
    }
}

// ---------- input projection + LN (+ bf16 hi/lo split of x) ----------
__global__ __launch_bounds__(256) void k_input_ln(
    const float* __restrict__ inputs, const float* __restrict__ in_w,
    const float* __restrict__ in_b, float* __restrict__ x,
    unsigned short* __restrict__ xh, unsigned short* __restrict__ xl)
{
    __shared__ float red[8];
    int row = blockIdx.x;
    int d = threadIdx.x;
    float v = inputs[row] * in_w[d] + in_b[d];
    float2 mv = block_stats_256(v, red);
    float o = (v - mv.x) * rsqrtf(mv.y + EPS_);
    size_t idx = (size_t)row * D_ + d;
    x[idx] = o;
    unsigned short hb = f2bf(o);
    xh[idx] = hb;
    xl[idx] = f2bf(o - bf2f(hb));
}

// ---------- split-bf16 MFMA GEMM (BK=32 known-best) ----------
// (256,2): 2 blocks/CU — co-resident block covers staging latency.
// MODE 0: epilogue FUSES rope -> writes qr hi/lo directly (partner value via
//         __shfl_xor(v,1): col differs by 1 within the quad's 16 lanes).
// MODE 2 split-K-4: blockIdx.z = kz, partials summed in k_resid_ln.
#define PG 40   // LDS pitch (32 + 8)
template<int MODE>
__global__ __launch_bounds__(256, 2) void k_gemm_mfma(
    const unsigned short* __restrict__ Ah, const unsigned short* __restrict__ Al,
    const unsigned short* __restrict__ Wh, const unsigned short* __restrict__ Wl,
    const unsigned short* __restrict__ xsh, const unsigned short* __restrict__ xsl,
    unsigned short* __restrict__ outh, unsigned short* __restrict__ outl,
    float* __restrict__ outf,
    unsigned short* __restrict__ qrh, unsigned short* __restrict__ qrl)
{
    constexpr int K = (MODE == 2) ? 1024 : 256;
    __shared__ unsigned short As_h[128 * PG], As_l[128 * PG];
    __shared__ unsigned short Ws_h[128 * PG], Ws_l[128 * PG];
    int tid = threadIdx.x;
    int w = tid >> 6, lane = tid & 63, quad = lane >> 4, l16 = lane & 15;
    int wm = w >> 1, wn = w & 1;
    int m0 = blockIdx.y * 128, n0x = blockIdx.x * 128;
    size_t a_row0, w_row0, out_row0;
    int col0;
    int koff = 0, kend = K;
    if (MODE == 1) {
        int bh = blockIdx.z;
        a_row0 = (size_t)bh * 1024 + m0;
        w_row0 = (size_t)((bh & 3) * 256 + n0x);
        out_row0 = (size_t)(bh >> 2) * 1024 + m0;
        col0 = (bh & 3) * 256 + n0x;
    } else {
        a_row0 = m0; w_row0 = n0x; out_row0 = m0; col0 = n0x;
        if (MODE == 2) { koff = blockIdx.z * 256; kend = koff + 256; }
    }
    floatx4 acc[4][4];
    #pragma unroll
    for (int mt = 0; mt < 4; mt++)
        #pragma unroll
        for (int nt = 0; nt < 4; nt++)
            acc[mt][nt] = (floatx4){0.f, 0.f, 0.f, 0.f};

    for (int k0 = koff; k0 < kend; k0 += 32) {
        #pragma unroll
        for (int it = 0; it < 2; it++) {
            int fl = tid + it * 256;
            int row = fl >> 2, ch = fl & 3;
            size_t ga = (a_row0 + row) * (size_t)K + k0 + ch * 8;
            size_t gw = (w_row0 + row) * (size_t)K + k0 + ch * 8;
            *(short8_t*)&As_h[row * PG + ch * 8] = *(const short8_t*)(Ah + ga);
            *(short8_t*)&As_l[row * PG + ch * 8] = *(const short8_t*)(Al + ga);
            *(short8_t*)&Ws_h[row * PG + ch * 8] = *(const short8_t*)(Wh + gw);
            *(short8_t*)&Ws_l[row * PG + ch * 8] = *(const short8_t*)(Wl + gw);
        }
        __syncthreads();
        short8_t afh[4], afl[4], bfh[4], bfl[4];
        #pragma unroll
        for (int mt = 0; mt < 4; mt++) {
            afh[mt] = *(const short8_t*)&As_h[(wm * 64 + mt * 16 + l16) * PG + quad * 8];
            afl[mt] = *(const short8_t*)&As_l[(wm * 64 + mt * 16 + l16) * PG + quad * 8];
        }
        #pragma unroll
        for (int nt = 0; nt < 4; nt++) {
            bfh[nt] = *(const short8_t*)&Ws_h[(wn * 64 + nt * 16 + l16) * PG + quad * 8];
            bfl[nt] = *(const short8_t*)&Ws_l[(wn * 64 + nt * 16 + l16) * PG + quad * 8];
        }
        #pragma unroll
        for (int mt = 0; mt < 4; mt++)
            #pragma unroll
            for (int nt = 0; nt < 4; nt++) {
                acc[mt][nt] = __builtin_amdgcn_mfma_f32_16x16x32_bf16(afh[mt], bfh[nt], acc[mt][nt], 0, 0, 0);
                acc[mt][nt] = __builtin_amdgcn_mfma_f32_16x16x32_bf16(afh[mt], bfl[nt], acc[mt][nt], 0, 0, 0);
                acc[mt][nt] = __builtin_amdgcn_mfma_f32_16x16x32_bf16(afl[mt], bfh[nt], acc[mt][nt], 0, 0, 0);
            }
        __syncthreads();
    }

    #pragma unroll
    for (int mt = 0; mt < 4; mt++) {
        #pragma unroll
        for (int r = 0; r < 4; r++) {
            size_t grow = out_row0 + wm * 64 + mt * 16 + quad * 4 + r;
            #pragma unroll
            for (int nt = 0; nt < 4; nt++) {
                int gcol = col0 + wn * 64 + nt * 16 + l16;
                float v = acc[mt][nt][r];
                if (MODE == 0) {
                    v = fmaxf(v, 0.f);
                    size_t o = grow * 1024 + gcol;
                    unsigned short hb = f2bf(v);
                    outh[o] = hb;
                    outl[o] = f2bf(v - bf2f(hb));
                    // fused rope: partner col (n^1) lives in lane l16^1
                    float vp = __shfl_xor(v, 1);
                    int n = gcol & 255, h = gcol >> 8;
                    int t = (int)(grow & 1023), b = (int)(grow >> 10);
                    int p = n >> 1, j = p & 63;
                    int pos = (p < 64) ? (t & 31) : (t >> 5);
                    float f = __expf((float)j * -0.14391156f);
                    float ang = (float)pos * f;
                    float sn = __sinf(ang), cs = __cosf(ang);
                    float ro = (n & 1) ? (vp * sn + v * cs) : (v * cs - vp * sn);
                    size_t qo = (((size_t)b * NH_ + h) * T_ + t) * N_ + n;
                    unsigned short qb = f2bf(ro);
                    qrh[qo] = qb;
                    qrl[qo] = f2bf(ro - bf2f(qb));
                } else if (MODE == 1) {
                    float y = fmaxf(v, 0.f);
                    size_t o = grow * 1024 + gcol;
                    float xv = bf2f(xsh[o]) + bf2f(xsl[o]);
                    float p = xv * y;
                    unsigned short hb = f2bf(p);
                    outh[o] = hb;
                    outl[o] = f2bf(p - bf2f(hb));
                } else {
                    outf[(size_t)blockIdx.z * 2097152 + grow * 256 + gcol] = v;
                }
            }
        }
    }
}

// ---------- x (B,T,D) fp32 -> Vf hi/lo fragment-order bf16 ----------
__global__ __launch_bounds__(256) void k_xT(const float* __restrict__ x,
                                            unsigned short* __restrict__ Vfh,
                                            unsigned short* __restrict__ Vfl)
{
    __shared__ float tile[64][65];   // [t_local][d_local]
    int t0 = blockIdx.x * 64, d0 = blockIdx.y * 64, b = blockIdx.z;
    const float* src = x + ((size_t)b * T_ + t0) * D_ + d0;
    for (int i = threadIdx.x; i < 1024; i += 256) {
        int r = i >> 4, c = i & 15;
        float4 v = *(const float4*)(src + (size_t)r * D_ + c * 4);
        tile[r][c * 4 + 0] = v.x;
        tile[r][c * 4 + 1] = v.y;
        tile[r][c * 4 + 2] = v.z;
        tile[r][c * 4 + 3] = v.w;
    }
    __syncthreads();
    for (int i = threadIdx.x; i < 1024; i += 256) {
        int d = i >> 4, c = i & 15;          // d_local, t-group (4 consecutive t)
        int tg = t0 + c * 4;
        int jj = tg >> 5, qd = (tg >> 3) & 3, i8 = tg & 7;   // i8 in {0,4}
        int dg = d0 + d;
        int tn = dg >> 4, s16 = dg & 15;
        size_t o = (((size_t)b * 32 + jj) * 16 + tn) * 512 + (qd * 16 + s16) * 8 + i8;
        float v0 = tile[c * 4 + 0][d], v1 = tile[c * 4 + 1][d];
        float v2 = tile[c * 4 + 2][d], v3 = tile[c * 4 + 3][d];
        ushort4 oh, ol;
        oh.x = f2bf(v0); ol.x = f2bf(v0 - bf2f(oh.x));
        oh.y = f2bf(v1); ol.y = f2bf(v1 - bf2f(oh.y));
        oh.z = f2bf(v2); ol.z = f2bf(v2 - bf2f(oh.z));
        oh.w = f2bf(v3); ol.w = f2bf(v3 - bf2f(oh.w));
        *(ushort4*)(Vfh + o) = oh;
        *(ushort4*)(Vfl + o) = ol;
    }
}

// ---------- fused split-bf16 MFMA flash attention + /l + LayerNorm ----------
// (unchanged: V-LDS dbuf + fixed-shift softmax + QK ILP)
#define PPW 36   // per-wave P pitch (32 + 4)

__global__ __launch_bounds__(512, 1) void k_attn_mfma(
    const unsigned short* __restrict__ qr_h, const unsigned short* __restrict__ qr_l,
    const unsigned short* __restrict__ Vf_h, const unsigned short* __restrict__ Vf_l,
    unsigned short* __restrict__ ykvh, unsigned short* __restrict__ ykvl)
{
    __shared__ unsigned short K_h[2][16 * 512];   // 32 KB (2 buf, frag order)
    __shared__ unsigned short K_l[2][16 * 512];   // 32 KB
    __shared__ unsigned short V_h[2][16 * 512];   // 32 KB
    __shared__ unsigned short V_l[2][16 * 512];   // 32 KB
    __shared__ unsigned short P_h[8][16 * PPW];   // 9216 B (per-wave private)
    __shared__ unsigned short P_l[8][16 * PPW];   // 9216 B

    int tid = threadIdx.x;
    int w = tid >> 6, lane = tid & 63, quad = lane >> 4, l16 = lane & 15;
    int gid = blockIdx.x;
    int bh = gid & 31, tile = gid >> 5, b = bh >> 2;   // XCD swizzle
    int t0q = tile * 128;
    const unsigned short* qhb = qr_h + (size_t)bh * T_ * N_;
    const unsigned short* qlb = qr_l + (size_t)bh * T_ * N_;
    const unsigned short* vhb = Vf_h + (size_t)b * 32 * 16 * 512;
    const unsigned short* vlb = Vf_l + (size_t)b * 32 * 16 * 512;

    // Q A-frags: wave's 16 rows, full feature dim (8 kc chunks), hi+lo
    short8_t qfh[8], qfl[8];
    #pragma unroll
    for (int kc = 0; kc < 8; kc++) {
        size_t o = (size_t)(t0q + w * 16 + l16) * N_ + kc * 32 + quad * 8;
        qfh[kc] = *(const short8_t*)(qhb + o);
        qfl[kc] = *(const short8_t*)(qlb + o);
    }

    floatx4 O[16];
    #pragma unroll
    for (int tn = 0; tn < 16; tn++) O[tn] = (floatx4){0.f, 0.f, 0.f, 0.f};
    float lst[4] = {0.f, 0.f, 0.f, 0.f};   // per-LANE partial row sums
    const float scale = 0.0625f;   // 1/sqrt(256)

    // preamble: stage K and V tile 0 into buffer 0 (wave w: slots 2w, 2w+1)
    #pragma unroll
    for (int s = 0; s < 2; s++) {
        int slot = w * 2 + s;
        int ct = slot >> 3, kc = slot & 7;
        size_t go = (size_t)(ct * 16 + l16) * N_ + kc * 32 + quad * 8;
        gload_lds16(qhb + go, &K_h[0][slot * 512]);
        gload_lds16(qlb + go, &K_l[0][slot * 512]);
        size_t vo = ((size_t)slot << 9) + lane * 8;
        gload_lds16(vhb + vo, &V_h[0][slot * 512]);
        gload_lds16(vlb + vo, &V_l[0][slot * 512]);
    }

    for (int j = 0; j < 32; j++) {
        int buf = j & 1;
        __syncthreads();            // tiles j ready; buf^1 free
        if (j < 31) {               // async-stage K & V tile j+1 (full step to land)
            #pragma unroll
            for (int s = 0; s < 2; s++) {
                int slot = w * 2 + s;
                int ct = slot >> 3, kc = slot & 7;
                size_t go = (size_t)((j + 1) * 32 + ct * 16 + l16) * N_ + kc * 32 + quad * 8;
                gload_lds16(qhb + go, &K_h[buf ^ 1][slot * 512]);
                gload_lds16(qlb + go, &K_l[buf ^ 1][slot * 512]);
                size_t vo = ((size_t)((j + 1) * 16 + slot) << 9) + lane * 8;
                gload_lds16(vhb + vo, &V_h[buf ^ 1][slot * 512]);
                gload_lds16(vlb + vo, &V_l[buf ^ 1][slot * 512]);
            }
        }

        // QK^T: 3 independent accumulator chains per ct (ILP)
        floatx4 sc[2];
        #pragma unroll
        for (int ct = 0; ct < 2; ct++) {
            floatx4 a_hh = (floatx4){0.f, 0.f, 0.f, 0.f};
            floatx4 a_hl = (floatx4){0.f, 0.f, 0.f, 0.f};
            floatx4 a_lh = (floatx4){0.f, 0.f, 0.f, 0.f};
            #pragma unroll
            for (int kc = 0; kc < 8; kc++) {
                short8_t bkh = *(const short8_t*)&K_h[buf][(ct * 8 + kc) * 512 + lane * 8];
                short8_t bkl = *(const short8_t*)&K_l[buf][(ct * 8 + kc) * 512 + lane * 8];
                a_hh = __builtin_amdgcn_mfma_f32_16x16x32_bf16(qfh[kc], bkh, a_hh, 0, 0, 0);
                a_hl = __builtin_amdgcn_mfma_f32_16x16x32_bf16(qfh[kc], bkl, a_hl, 0, 0, 0);
                a_lh = __builtin_amdgcn_mfma_f32_16x16x32_bf16(qfl[kc], bkh, a_lh, 0, 0, 0);
            }
            sc[ct] = (a_hh + a_hl) + a_lh;
        }

        // fixed-shift softmax (row = w*16 + quad*4 + r); no cross-lane ops
        #pragma unroll
        for (int r = 0; r < 4; r++) {
            float p0 = __expf(sc[0][r] * scale - 8.f);
            float p1 = __expf(sc[1][r] * scale - 8.f);
            lst[r] += p0 + p1;
            unsigned short p0h = f2bf(p0), p1h = f2bf(p1);
            P_h[w][(quad * 4 + r) * PPW + l16]      = p0h;
            P_h[w][(quad * 4 + r) * PPW + 16 + l16] = p1h;
            P_l[w][(quad * 4 + r) * PPW + l16]      = f2bf(p0 - bf2f(p0h));
            P_l[w][(quad * 4 + r) * PPW + 16 + l16] = f2bf(p1 - bf2f(p1h));
        }

        // P C-layout -> A-layout via same-wave LDS round-trip (no barrier)
        short8_t pah = *(const short8_t*)&P_h[w][l16 * PPW + quad * 8];
        short8_t pal = *(const short8_t*)&P_l[w][l16 * PPW + quad * 8];

        // PV (split 3-term): V frags from LDS, conflict-free ds_read_b128
        #pragma unroll
        for (int tn = 0; tn < 16; tn++) {
            short8_t vbh = *(const short8_t*)&V_h[buf][tn * 512 + lane * 8];
            short8_t vbl = *(const short8_t*)&V_l[buf][tn * 512 + lane * 8];
            O[tn] = __builtin_amdgcn_mfma_f32_16x16x32_bf16(pah, vbh, O[tn], 0, 0, 0);
            O[tn] = __builtin_amdgcn_mfma_f32_16x16x32_bf16(pah, vbl, O[tn], 0, 0, 0);
            O[tn] = __builtin_amdgcn_mfma_f32_16x16x32_bf16(pal, vbh, O[tn], 0, 0, 0);
        }
    }

    // epilogue: reduce l across the quad's 16 lanes, then yKV = LN_d(O / l)
    size_t obase = ((size_t)bh * T_ + t0q + w * 16) * D_;
    #pragma unroll
    for (int r = 0; r < 4; r++) {
        float lsum = lst[r];
        #pragma unroll
        for (int o = 1; o < 16; o <<= 1) lsum += __shfl_xor(lsum, o);
        float li = 1.f / lsum;
        float s1 = 0.f, s2 = 0.f;
        #pragma unroll
        for (int tn = 0; tn < 16; tn++) { float v = O[tn][r]; s1 += v; s2 += v * v; }
        #pragma unroll
        for (int o = 1; o < 16; o <<= 1) { s1 += __shfl_xor(s1, o); s2 += __shfl_xor(s2, o); }
        float mean = s1 * li * (1.f / 256.f);
        float e2   = s2 * li * li * (1.f / 256.f);
        float var  = e2 - mean * mean;
        float rs = rsqrtf(var + EPS_);
        float a = li * rs, bb = mean * rs;
        int row = quad * 4 + r;
        #pragma unroll
        for (int tn = 0; tn < 16; tn++) {
            float v = O[tn][r] * a - bb;
            size_t o = obase + (size_t)row * D_ + tn * 16 + l16;
            unsigned short hb = f2bf(v);
            ykvh[o] = hb;
            ykvl[o] = f2bf(v - bf2f(hb));
        }
    }
}

// ---------- residual + double LN: sums 4 split-K partials of ymlp ----------
__global__ __launch_bounds__(256) void k_resid_ln(float* __restrict__ x,
                                                  const float* __restrict__ ymlp,
                                                  unsigned short* __restrict__ xh,
                                                  unsigned short* __restrict__ xl)
{
    __shared__ float red[8];
    int row = blockIdx.x, d = threadIdx.x;
    size_t o = (size_t)row * D_ + d;
    float y = ymlp[o] + ymlp[o + 2097152] + ymlp[o + 2 * 2097152] + ymlp[o + 3 * 2097152];
    float2 mv1 = block_stats_256(y, red);
    float v = x[o] + (y - mv1.x) * rsqrtf(mv1.y + EPS_);
    float2 mv2 = block_stats_256(v, red);
    float out = (v - mv2.x) * rsqrtf(mv2.y + EPS_);
    x[o] = out;
    unsigned short hb = f2bf(out);
    xh[o] = hb;
    xl[o] = f2bf(out - bf2f(hb));
}

// ---------- logits ----------
__global__ __launch_bounds__(256) void k_logits(
    const float* __restrict__ x, const float* __restrict__ out_w,
    const float* __restrict__ out_b, float* __restrict__ out)
{
    __shared__ float red[4];
    int row = blockIdx.x, d = threadIdx.x;
    float v = x[(size_t)row * D_ + d] * out_w[d];
    #pragma unroll
    for (int o = 32; o > 0; o >>= 1) v += __shfl_down(v, o);
    int wave = d >> 6, lane = d & 63;
    if (lane == 0) red[wave] = v;
    __syncthreads();
    if (d == 0) out[row] = red[0] + red[1] + red[2] + red[3] + out_b[0];
}

extern "C" void kernel_launch(void* const* d_in, const int* in_sizes, int n_in,
                              void* d_out, int out_size, void* d_ws, size_t ws_size,
                              hipStream_t stream)
{
    (void)in_sizes; (void)n_in; (void)out_size;
    if (ws_size < ((size_t)115 << 20)) return;

    const float* inputs    = (const float*)d_in[0];
    const float* in_w      = (const float*)d_in[1];
    const float* in_b      = (const float*)d_in[2];
    const float* encoder   = (const float*)d_in[3];
    const float* encoder_v = (const float*)d_in[4];
    const float* decoder   = (const float*)d_in[5];
    const float* out_w     = (const float*)d_in[6];
    const float* out_b     = (const float*)d_in[7];

    char* wsb = (char*)d_ws;
    float* x             = (float*)(wsb);                                 //  8 MB fp32 (B,T,D)
    unsigned short* x_h  = (unsigned short*)(wsb + ((size_t)8  << 20));   //  4 MB bf16 hi
    unsigned short* x_l  = (unsigned short*)(wsb + ((size_t)12 << 20));   //  4 MB lo
    unsigned short* Vf_h = x_h;                                           //  ALIAS (disjoint phases)
    unsigned short* Vf_l = x_l;
    unsigned short* xs_h = (unsigned short*)(wsb + ((size_t)16 << 20));   // 16 MB (B,T,NH*N) hi
    unsigned short* xs_l = (unsigned short*)(wsb + ((size_t)32 << 20));   // 16 MB lo
    float* ymlp          = (float*)(wsb + ((size_t)16 << 20));            // 32 MB fp32 x4 partials,
                                                                          //  ALIASES xs (dead there)
    unsigned short* qr_h = (unsigned short*)(wsb + ((size_t)48 << 20));   // 16 MB (B,NH,T,N) hi
    unsigned short* qr_l = (unsigned short*)(wsb + ((size_t)64 << 20));   // 16 MB lo
    unsigned short* xy_h = qr_h;                                          //  ALIAS: xy after attn
    unsigned short* xy_l = qr_l;
    unsigned short* ykv_h = (unsigned short*)(wsb + ((size_t)80 << 20));  // 16 MB (B,NH,T,D) hi
    unsigned short* ykv_l = (unsigned short*)(wsb + ((size_t)96 << 20));  // 16 MB lo
    char* wbase = wsb + ((size_t)112 << 20);                              //  3 MB weights
    unsigned short* encT_h = (unsigned short*)(wbase);
    unsigned short* encT_l = (unsigned short*)(wbase + 0x80000);
    unsigned short* evT_h  = (unsigned short*)(wbase + 2 * 0x80000);
    unsigned short* evT_l  = (unsigned short*)(wbase + 3 * 0x80000);
    unsigned short* decT_h = (unsigned short*)(wbase + 4 * 0x80000);
    unsigned short* decT_l = (unsigned short*)(wbase + 5 * 0x80000);

    k_wT<<<dim3(4, 4, 4), 256, 0, stream>>>(encoder,   encT_h, encT_l, 256, 256);
    k_wT<<<dim3(4, 4, 4), 256, 0, stream>>>(encoder_v, evT_h,  evT_l,  256, 256);
    k_wT<<<dim3(4, 16, 1), 256, 0, stream>>>(decoder,  decT_h, decT_l, 1024, 256);

    k_input_ln<<<B_ * T_, 256, 0, stream>>>(inputs, in_w, in_b, x, x_h, x_l);
    for (int l = 0; l < 3; l++) {
        k_gemm_mfma<0><<<dim3(8, 64, 1), 256, 0, stream>>>(
            x_h, x_l, encT_h, encT_l, nullptr, nullptr, xs_h, xs_l, nullptr, qr_h, qr_l);
        k_xT<<<dim3(16, 4, 8), 256, 0, stream>>>(x, Vf_h, Vf_l);
        k_attn_mfma<<<256, 512, 0, stream>>>(qr_h, qr_l, Vf_h, Vf_l, ykv_h, ykv_l);
        k_gemm_mfma<1><<<dim3(2, 8, 32), 256, 0, stream>>>(
            ykv_h, ykv_l, evT_h, evT_l, xs_h, xs_l, xy_h, xy_l, nullptr, nullptr, nullptr);
        k_gemm_mfma<2><<<dim3(2, 64, 4), 256, 0, stream>>>(
            xy_h, xy_l, decT_h, decT_l, nullptr, nullptr, nullptr, nullptr, ymlp, nullptr, nullptr);
        k_resid_ln<<<B_ * T_, 256, 0, stream>>>(x, ymlp, x_h, x_l);
    }
    k_logits<<<B_ * T_, 256, 0, stream>>>(x, out_w, out_b, (float*)d_out);
}